// Round 10
// baseline (4390.499 us; speedup 1.0000x reference)
//
#include <hip/hip_runtime.h>
#include <hip/hip_bf16.h>
#include <math.h>

#define HDIM 768
#define SDIM 512
#define VDIM 30522
#define BDIM 8
#define TLEN 32
#define H3   2304
#define VT   31034          // V + S
#define NEGV -1.0e6f
#define OFF2 ((size_t)BDIM * TLEN * VT)   // 7944704
#define NSUB 32                            // s/v subslices
#define SSL  16                            // SDIM / NSUB
#define VSL  954                           // ceil(VDIM/32)
#define NROWS (HDIM + VDIM + HDIM + H3)    // 34362 bigmv rows

// ---------------------------------------------------------------------------
// Boot: dout init; h0 = 0; th0 = attn_b; gh0 = b_hh; x sel/emb init.
// ---------------------------------------------------------------------------
__global__ __launch_bounds__(256) void boot_kernel(
    float* __restrict__ dout, const int* __restrict__ cls,
    float* __restrict__ hA, float* __restrict__ x,
    const float* __restrict__ emb, float* __restrict__ thb,
    float* __restrict__ ghb, const float* __restrict__ attn_b,
    const float* __restrict__ b_hh)
{
    int gidx = blockIdx.x * 256 + threadIdx.x;
    int stride = gridDim.x * 256;
    float clsv = (float)cls[0];
    for (int i = gidx; i < BDIM * VT; i += stride) {
        int b = i / VT, v = i % VT;
        dout[(size_t)b * TLEN * VT + v] = (v == 0) ? clsv : 0.f;
    }
    if (gidx < BDIM) dout[OFF2 + (size_t)gidx * TLEN] = 1.0f;
    for (int i = gidx; i < BDIM * HDIM; i += stride) {
        int b = i / HDIM, j = i % HDIM;
        hA[i] = 0.f;
        x[b * H3 + HDIM + j] = 0.f;
        x[b * H3 + 2 * HDIM + j] = emb[HDIM + j];
        thb[i] = attn_b[j];
    }
    for (int i = gidx; i < BDIM * H3; i += stride)
        ghb[i] = b_hh[i % H3];
}

// ---------------------------------------------------------------------------
// grufull: block j (768 blocks x 256 thr). 4 waves split K=2304 into 576-
// element chunks; per-wave partials for all 3 gates x 8 batches combined in
// LDS in fixed wave order; thread b<8 does the GRU nonlinearity.
// ---------------------------------------------------------------------------
__global__ __launch_bounds__(256) void grufull_kernel(
    const float* __restrict__ w_ih, const float* __restrict__ b_ih,
    const float* __restrict__ x, const float* __restrict__ ghb,
    const float* __restrict__ hin, float* __restrict__ hout)
{
    __shared__ float gp[4][3][BDIM];
    int tid = threadIdx.x, w = tid >> 6, lane = tid & 63;
    int j = blockIdx.x;

    const float4* wr = (const float4*)(w_ih + (size_t)j * H3);
    const float4* wz = (const float4*)(w_ih + (size_t)(HDIM + j) * H3);
    const float4* wn = (const float4*)(w_ih + (size_t)(2 * HDIM + j) * H3);

    float ar[8], az[8], an[8];
#pragma unroll
    for (int b = 0; b < 8; b++) { ar[b] = 0.f; az[b] = 0.f; an[b] = 0.f; }

    int k0 = w * 144;                       // 144 float4 = 576 floats per wave
    for (int k4 = k0 + lane; k4 < k0 + 144; k4 += 64) {
        float4 w4r = wr[k4], w4z = wz[k4], w4n = wn[k4];
#pragma unroll
        for (int b = 0; b < 8; b++) {
            float4 x4 = ((const float4*)(x + b * H3))[k4];
            ar[b] += w4r.x * x4.x + w4r.y * x4.y + w4r.z * x4.z + w4r.w * x4.w;
            az[b] += w4z.x * x4.x + w4z.y * x4.y + w4z.z * x4.z + w4z.w * x4.w;
            an[b] += w4n.x * x4.x + w4n.y * x4.y + w4n.z * x4.z + w4n.w * x4.w;
        }
    }
#pragma unroll
    for (int b = 0; b < 8; b++) {
        float vr = ar[b], vz = az[b], vn = an[b];
        for (int off = 32; off; off >>= 1) {
            vr += __shfl_down(vr, off, 64);
            vz += __shfl_down(vz, off, 64);
            vn += __shfl_down(vn, off, 64);
        }
        ar[b] = vr; az[b] = vz; an[b] = vn;
    }
    if (lane == 0) {
#pragma unroll
        for (int b = 0; b < 8; b++) {
            gp[w][0][b] = ar[b];
            gp[w][1][b] = az[b];
            gp[w][2][b] = an[b];
        }
    }
    __syncthreads();
    if (tid < BDIM) {
        int b = tid;
        float gir = gp[0][0][b] + gp[1][0][b] + gp[2][0][b] + gp[3][0][b] + b_ih[j];
        float giz = gp[0][1][b] + gp[1][1][b] + gp[2][1][b] + gp[3][1][b] + b_ih[HDIM + j];
        float gin = gp[0][2][b] + gp[1][2][b] + gp[2][2][b] + gp[3][2][b] + b_ih[2 * HDIM + j];
        float ghr = ghb[b * H3 + j];
        float ghz = ghb[b * H3 + HDIM + j];
        float ghn = ghb[b * H3 + 2 * HDIM + j];
        float r = 1.f / (1.f + expf(-(gir + ghr)));
        float z = 1.f / (1.f + expf(-(giz + ghz)));
        float n = tanhf(gin + r * ghn);
        hout[b * HDIM + j] = (1.f - z) * n + z * hin[b * HDIM + j];
    }
}

// ---------------------------------------------------------------------------
// Per-row routing for bigmv.
// ---------------------------------------------------------------------------
struct RowT { const float* w; const float* bias; float* dst; int stride; int neg; };

__device__ __forceinline__ RowT row_info(
    int r,
    const float* copy_w, const float* copy_b,
    const float* out_w,  const float* out_b,
    const float* attn_w, const float* attn_b,
    const float* w_hh,   const float* b_hh,
    float* th2, float* gen, float* thb, float* ghb)
{
    RowT t;
    if (r < HDIM) {
        t.w = copy_w + (size_t)r * HDIM; t.bias = copy_b + r;
        t.dst = th2 + r; t.stride = HDIM; t.neg = 0;
    } else if (r < HDIM + VDIM) {
        int v = r - HDIM;
        t.w = out_w + (size_t)v * HDIM; t.bias = out_b + v;
        t.dst = gen + v; t.stride = VDIM; t.neg = (v == 0);
    } else if (r < 2 * HDIM + VDIM) {
        int rr = r - HDIM - VDIM;
        t.w = attn_w + (size_t)rr * HDIM; t.bias = attn_b + rr;
        t.dst = thb + rr; t.stride = HDIM; t.neg = 0;
    } else {
        int rr = r - 2 * HDIM - VDIM;
        t.w = w_hh + (size_t)rr * HDIM; t.bias = b_hh + rr;
        t.dst = ghb + rr; t.stride = H3; t.neg = 0;
    }
    return t;
}

// ---------------------------------------------------------------------------
// bigmv: stream copy_w | out_w | attn_w | w_hh against x read directly from
// global (hp = 24 KB, L1/L2-hot). 2148 blocks x 256 thr; 4 waves x 4 rows.
// ---------------------------------------------------------------------------
__global__ __launch_bounds__(256, 8) void bigmv_kernel(
    const float* __restrict__ copy_w, const float* __restrict__ copy_b,
    const float* __restrict__ out_w,  const float* __restrict__ out_b,
    const float* __restrict__ attn_w, const float* __restrict__ attn_b,
    const float* __restrict__ w_hh,   const float* __restrict__ b_hh,
    const float* __restrict__ hp, float* __restrict__ th2,
    float* __restrict__ gen, float* __restrict__ thb,
    float* __restrict__ ghb)
{
    int wid = threadIdx.x >> 6, lane = threadIdx.x & 63;
    int r0 = blockIdx.x * 16 + wid * 4;
    if (r0 >= NROWS) return;

    int rc1 = min(r0 + 1, NROWS - 1);
    int rc2 = min(r0 + 2, NROWS - 1), rc3 = min(r0 + 3, NROWS - 1);
    RowT t0 = row_info(r0,  copy_w, copy_b, out_w, out_b, attn_w, attn_b,
                       w_hh, b_hh, th2, gen, thb, ghb);
    RowT t1 = row_info(rc1, copy_w, copy_b, out_w, out_b, attn_w, attn_b,
                       w_hh, b_hh, th2, gen, thb, ghb);
    RowT t2 = row_info(rc2, copy_w, copy_b, out_w, out_b, attn_w, attn_b,
                       w_hh, b_hh, th2, gen, thb, ghb);
    RowT t3 = row_info(rc3, copy_w, copy_b, out_w, out_b, attn_w, attn_b,
                       w_hh, b_hh, th2, gen, thb, ghb);

    float a0[8], a1[8], a2[8], a3[8];
#pragma unroll
    for (int b = 0; b < 8; b++) { a0[b] = 0.f; a1[b] = 0.f; a2[b] = 0.f; a3[b] = 0.f; }

    const float4* w0 = (const float4*)t0.w;
    const float4* w1 = (const float4*)t1.w;
    const float4* w2 = (const float4*)t2.w;
    const float4* w3 = (const float4*)t3.w;
    const float4* xb = (const float4*)hp;

#pragma unroll
    for (int i = 0; i < 3; i++) {
        int k4 = lane + i * 64;
        float4 q0 = w0[k4], q1 = w1[k4], q2 = w2[k4], q3 = w3[k4];
#pragma unroll
        for (int b = 0; b < 8; b++) {
            float4 x4 = xb[b * 192 + k4];
            a0[b] += q0.x * x4.x + q0.y * x4.y + q0.z * x4.z + q0.w * x4.w;
            a1[b] += q1.x * x4.x + q1.y * x4.y + q1.z * x4.z + q1.w * x4.w;
            a2[b] += q2.x * x4.x + q2.y * x4.y + q2.z * x4.z + q2.w * x4.w;
            a3[b] += q3.x * x4.x + q3.y * x4.y + q3.z * x4.z + q3.w * x4.w;
        }
    }
#pragma unroll
    for (int b = 0; b < 8; b++) {
        float v0 = a0[b], v1 = a1[b], v2 = a2[b], v3 = a3[b];
        for (int off = 32; off; off >>= 1) {
            v0 += __shfl_down(v0, off, 64);
            v1 += __shfl_down(v1, off, 64);
            v2 += __shfl_down(v2, off, 64);
            v3 += __shfl_down(v3, off, 64);
        }
        a0[b] = v0; a1[b] = v1; a2[b] = v2; a3[b] = v3;
    }
    if (lane == 0) {
        float bb0 = t0.bias[0], bb1 = t1.bias[0], bb2 = t2.bias[0], bb3 = t3.bias[0];
#pragma unroll
        for (int b = 0; b < 8; b++) {
            t0.dst[(size_t)b * t0.stride] = t0.neg ? NEGV : a0[b] + bb0;
            if (r0 + 1 < NROWS) t1.dst[(size_t)b * t1.stride] = t1.neg ? NEGV : a1[b] + bb1;
            if (r0 + 2 < NROWS) t2.dst[(size_t)b * t2.stride] = t2.neg ? NEGV : a2[b] + bb2;
            if (r0 + 3 < NROWS) t3.dst[(size_t)b * t3.stride] = t3.neg ? NEGV : a3[b] + bb3;
        }
    }
}

// ---------------------------------------------------------------------------
// combo: block (b,sub): one enc pass. Each wave dots 2 enc rows against th
// (scores t+1) AND th2 (css), KEEPING the enc fragments in registers; after
// the softmax partial, per-wave context partials go to LDS and are summed in
// fixed wave order. Then gen-stats slice. 256 blocks x 512.
// ---------------------------------------------------------------------------
__global__ __launch_bounds__(512) void combo_kernel(
    const float* __restrict__ enc, const float* __restrict__ thb,
    const float* __restrict__ th2, float* __restrict__ css,
    float* __restrict__ atC, float* __restrict__ atM, float* __restrict__ atZ,
    const float* __restrict__ gen, float* __restrict__ gM,
    float* __restrict__ gZ, int do_cg)
{
    __shared__ float sth[HDIM];
    __shared__ float sth2[HDIM];
    __shared__ float swe[SSL];
    __shared__ float red[8];
    __shared__ float4 part[8][HDIM / 4];   // 24 KB
    int blk = blockIdx.x, b = blk >> 5, sub = blk & 31;
    int tid = threadIdx.x, wid = tid >> 6, lane = tid & 63;
    int slo = sub * SSL;

    for (int i = tid; i < HDIM; i += 512) {
        sth[i]  = thb[b * HDIM + i];
        sth2[i] = th2[b * HDIM + i];
    }
    __syncthreads();

    // dual dots: 2 s per wave; keep enc fragments live
    float4 e0[3], e1[3];
#pragma unroll
    for (int j = 0; j < 2; j++) {
        int sl = wid * 2 + j, s = slo + sl;
        const float4* er = (const float4*)(enc + ((size_t)b * SDIM + s) * HDIM);
        float a1 = 0.f, a2 = 0.f;
#pragma unroll
        for (int i = 0; i < 3; i++) {
            float4 e = er[lane + i * 64];
            if (j == 0) e0[i] = e; else e1[i] = e;
            float4 t1 = ((const float4*)sth)[lane + i * 64];
            float4 t2 = ((const float4*)sth2)[lane + i * 64];
            a1 += e.x * t1.x + e.y * t1.y + e.z * t1.z + e.w * t1.w;
            a2 += e.x * t2.x + e.y * t2.y + e.z * t2.z + e.w * t2.w;
        }
        for (int off = 32; off; off >>= 1) {
            a1 += __shfl_down(a1, off, 64);
            a2 += __shfl_down(a2, off, 64);
        }
        if (lane == 0) {
            swe[sl] = a1;
            if (do_cg) css[b * SDIM + s] = a2;
        }
    }
    __syncthreads();

    // softmax partial over the 16 scores
    if (tid == 0) {
        float m = swe[0];
        for (int i = 1; i < SSL; i++) m = fmaxf(m, swe[i]);
        float z = 0.f;
        for (int i = 0; i < SSL; i++) { float e = expf(swe[i] - m); swe[i] = e; z += e; }
        atM[b * NSUB + sub] = m;
        atZ[b * NSUB + sub] = z;
    }
    __syncthreads();

    // per-wave context partial from live registers -> LDS
    {
        float wq0 = swe[wid * 2], wq1 = swe[wid * 2 + 1];
#pragma unroll
        for (int i = 0; i < 3; i++) {
            float4 p;
            p.x = wq0 * e0[i].x + wq1 * e1[i].x;
            p.y = wq0 * e0[i].y + wq1 * e1[i].y;
            p.z = wq0 * e0[i].z + wq1 * e1[i].z;
            p.w = wq0 * e0[i].w + wq1 * e1[i].w;
            part[wid][lane + i * 64] = p;
        }
    }
    __syncthreads();
    if (tid < HDIM / 4) {
        float4 acc = part[0][tid];
#pragma unroll
        for (int w = 1; w < 8; w++) {
            float4 p = part[w][tid];
            acc.x += p.x; acc.y += p.y; acc.z += p.z; acc.w += p.w;
        }
        ((float4*)(atC + ((size_t)b * NSUB + sub) * HDIM))[tid] = acc;
    }

    if (!do_cg) return;

    // gen stats over v-slice
    int vlo = sub * VSL, vhi = min(VDIM, vlo + VSL);
    const float* grow = gen + (size_t)b * VDIM;
    float m = -INFINITY;
    for (int v = vlo + tid; v < vhi; v += 512) m = fmaxf(m, grow[v]);
    for (int off = 32; off; off >>= 1) m = fmaxf(m, __shfl_xor(m, off, 64));
    if (lane == 0) red[wid] = m;
    __syncthreads();
    float M = red[0];
#pragma unroll
    for (int w = 1; w < 8; w++) M = fmaxf(M, red[w]);
    float z = 0.f;
    for (int v = vlo + tid; v < vhi; v += 512) z += expf(grow[v] - M);
    for (int off = 32; off; off >>= 1) z += __shfl_xor(z, off, 64);
    __syncthreads();
    if (lane == 0) red[wid] = z;
    __syncthreads();
    if (tid == 0) {
        float Z = 0.f;
#pragma unroll
        for (int w = 0; w < 8; w++) Z += red[w];
        gM[b * NSUB + sub] = M;
        gZ[b * NSUB + sub] = Z;
    }
}

// ---------------------------------------------------------------------------
// tailc: copy agg + M/Z combine (32 partials, fixed order) + log-prob slice
// + argmax partials. 256 blocks x 1024 (32 v-slices per batch).
// ---------------------------------------------------------------------------
__global__ __launch_bounds__(1024) void tailc_kernel(
    const float* __restrict__ gen, const float* __restrict__ css,
    const int* __restrict__ inputs, const float* __restrict__ genM,
    const float* __restrict__ genZ, float* __restrict__ dout,
    float* __restrict__ argV, int* __restrict__ argI, int t)
{
    __shared__ int   toks[SDIM];
    __shared__ float csss[SDIM];
    __shared__ float aggv[SDIM];
    __shared__ unsigned char ffl[SDIM];
    __shared__ float redf[1024];
    __shared__ int   redi[1024];
    int blk = blockIdx.x, b = blk >> 5, sub = blk & 31;
    int tid = threadIdx.x;

    if (tid < SDIM) {
        toks[tid] = inputs[b * SDIM + tid];
        csss[tid] = css[b * SDIM + tid];
    }
    __syncthreads();

    if (tid < SDIM) {
        int tok = toks[tid]; int isf = 0; float agg = -INFINITY;
        if (tok != 0) {
            isf = 1;
            for (int s2 = 0; s2 < tid; s2++)
                if (toks[s2] == tok) { isf = 0; break; }
            if (isf) {
                float ss = 0.f;
                for (int s2 = tid; s2 < SDIM; s2++)
                    if (toks[s2] == tok) ss += csss[s2];
                agg = ss;
            }
        }
        ffl[tid] = (unsigned char)isf;
        aggv[tid] = agg;
    }
    __syncthreads();

    redf[tid] = (tid < SDIM && ffl[tid]) ? aggv[tid] : -INFINITY;
    __syncthreads();
    for (int off = 512; off; off >>= 1) {
        if (tid < off) redf[tid] = fmaxf(redf[tid], redf[tid + off]);
        __syncthreads();
    }
    float m9 = redf[0]; __syncthreads();
    redf[tid] = (tid < SDIM && ffl[tid] && m9 > -INFINITY)
                    ? expf(aggv[tid] - m9) : 0.f;
    __syncthreads();
    for (int off = 512; off; off >>= 1) {
        if (tid < off) redf[tid] += redf[tid + off];
        __syncthreads();
    }
    float z9 = redf[0]; __syncthreads();

    float M = genM[b * NSUB + 0];
#pragma unroll
    for (int i = 1; i < NSUB; i++) M = fmaxf(M, genM[b * NSUB + i]);
    if (m9 > -INFINITY) M = fmaxf(M, m9);
    float Z = 0.f;
#pragma unroll
    for (int i = 0; i < NSUB; i++)
        Z += genZ[b * NSUB + i] * expf(genM[b * NSUB + i] - M);
    if (m9 > -INFINITY) Z += z9 * expf(m9 - M);
    float invZ = 1.f / Z;

    const float* grow = gen + (size_t)b * VDIM;
    float* orow = dout + ((size_t)b * TLEN + t + 1) * VT;
    int vlo = sub * VSL, vhi = min(VDIM, vlo + VSL);
    float best = -INFINITY; int bidx = 2147483647;
    for (int v = vlo + tid; v < vhi; v += 1024) {
        float pg = expf(grow[v] - M) * invZ;
        float lp = logf(pg + 1e-10f);
        orow[v] = lp;
        if (lp > best) { best = lp; bidx = v; }
    }
    if (sub == 0 && tid < SDIM) orow[VDIM + tid] = logf(1e-10f);
    __syncthreads();

    if (tid < SDIM && ffl[tid]) {
        int tok = toks[tid];
        if (tok >= vlo && tok < vhi) {
            float pc = expf(aggv[tid] - M) * invZ;
            float pg = expf(grow[tok] - M) * invZ;
            float lp = logf(pg + pc + 1e-10f);
            orow[tok] = lp;
            if (lp > best || (lp == best && tok < bidx)) { best = lp; bidx = tok; }
        }
    }
    redf[tid] = best; redi[tid] = bidx; __syncthreads();
    for (int off = 512; off; off >>= 1) {
        if (tid < off) {
            float v2 = redf[tid + off]; int i2 = redi[tid + off];
            if (v2 > redf[tid] || (v2 == redf[tid] && i2 < redi[tid])) {
                redf[tid] = v2; redi[tid] = i2;
            }
        }
        __syncthreads();
    }
    if (tid == 0) { argV[b * NSUB + sub] = redf[0]; argI[b * NSUB + sub] = redi[0]; }
}

// ---------------------------------------------------------------------------
// mix: blocks 0..7 = tail_d (argmax over 32 partials asc, samp, selread+embed)
//      blocks 8..15 = attn_fin (32-partial flash combine -> x[:,0:H)).
// ---------------------------------------------------------------------------
__global__ __launch_bounds__(1024) void mix_kernel(
    const float* __restrict__ enc, const float* __restrict__ css,
    const int* __restrict__ inputs, const float* __restrict__ argV,
    const int* __restrict__ argI, const float* __restrict__ emb,
    float* __restrict__ dout, float* __restrict__ x,
    const float* __restrict__ atC, const float* __restrict__ atM,
    const float* __restrict__ atZ, int t, int do_tail)
{
    __shared__ int   toks[SDIM];
    __shared__ float csss[SDIM];
    __shared__ float redf[1024];
    __shared__ int   mlist[SDIM];
    __shared__ float mscore[SDIM];
    __shared__ int   wcnt[16], woff[16];
    __shared__ int   mtot;
    int bid = blockIdx.x, tid = threadIdx.x;

    if (bid >= BDIM) {
        int b = bid - BDIM;
        if (tid < HDIM) {
            float M = atM[b * NSUB];
#pragma unroll
            for (int i = 1; i < NSUB; i++) M = fmaxf(M, atM[b * NSUB + i]);
            float Z = 0.f, acc = 0.f;
#pragma unroll
            for (int i = 0; i < NSUB; i++) {
                float sc = expf(atM[b * NSUB + i] - M);
                Z += atZ[b * NSUB + i] * sc;
                acc += atC[((size_t)b * NSUB + i) * HDIM + tid] * sc;
            }
            x[b * H3 + tid] = acc / Z;
        }
        return;
    }
    if (!do_tail) return;

    int b = bid;
    float best = argV[b * NSUB + 0]; int samp = argI[b * NSUB + 0];
#pragma unroll
    for (int i = 1; i < NSUB; i++) {
        float v = argV[b * NSUB + i];
        if (v > best) { best = v; samp = argI[b * NSUB + i]; }
    }
    if (tid == 0) dout[OFF2 + (size_t)b * TLEN + t + 1] = (float)samp;

    if (tid < SDIM) {
        toks[tid] = inputs[b * SDIM + tid];
        csss[tid] = css[b * SDIM + tid];
    }
    __syncthreads();

    int flag = (tid < SDIM) ? (toks[tid] == samp) : 0;
    redf[tid] = flag ? fabsf(csss[tid]) : 0.f;
    __syncthreads();
    for (int off = 512; off; off >>= 1) {
        if (tid < off) redf[tid] += redf[tid + off];
        __syncthreads();
    }
    float den = fmaxf(redf[0], 1e-12f);
    __syncthreads();

    unsigned long long mk = __ballot(flag);
    int wv = tid >> 6, ln = tid & 63;
    if (ln == 0) wcnt[wv] = __popcll(mk);
    __syncthreads();
    if (tid == 0) {
        int o = 0;
        for (int w = 0; w < 16; w++) { woff[w] = o; o += wcnt[w]; }
        mtot = o;
    }
    __syncthreads();
    if (flag) {
        int pos = woff[wv] + __popcll(mk & ((1ULL << ln) - 1ULL));
        mlist[pos] = tid;
        mscore[pos] = csss[tid] / den;
    }
    __syncthreads();
    int mc = mtot;

    if (tid < HDIM) {
        float sel = 0.f;
        for (int mI = 0; mI < mc; mI++)
            sel += mscore[mI] * enc[((size_t)b * SDIM + mlist[mI]) * HDIM + tid];
        x[b * H3 + HDIM + tid] = sel;
        int ic = (samp > VDIM) ? 3 : samp;
        if (ic >= VDIM) ic = VDIM - 1;
        x[b * H3 + 2 * HDIM + tid] = emb[(size_t)ic * HDIM + tid];
    }
}

// ---------------------------------------------------------------------------
extern "C" void kernel_launch(void* const* d_in, const int* in_sizes, int n_in,
                              void* d_out, int out_size, void* d_ws, size_t ws_size,
                              hipStream_t stream)
{
    const float* enc    = (const float*)d_in[0];
    const int*   inputs = (const int*)d_in[1];
    const int*   cls    = (const int*)d_in[2];
    const float* emb    = (const float*)d_in[4];
    const float* attn_w = (const float*)d_in[5];
    const float* attn_b = (const float*)d_in[6];
    const float* copy_w = (const float*)d_in[7];
    const float* copy_b = (const float*)d_in[8];
    const float* w_ih   = (const float*)d_in[9];
    const float* w_hh   = (const float*)d_in[10];
    const float* b_ih   = (const float*)d_in[11];
    const float* b_hh   = (const float*)d_in[12];
    const float* out_w  = (const float*)d_in[13];
    const float* out_b  = (const float*)d_in[14];
    float* dout = (float*)d_out;

    float* ws   = (float*)d_ws;
    float* hA   = ws;                          // B*H
    float* hB   = hA  + BDIM * HDIM;           // B*H
    float* x    = hB  + BDIM * HDIM;           // B*H3
    float* thb  = x   + BDIM * H3;             // B*H
    float* ghb  = thb + BDIM * HDIM;           // B*H3
    float* th2  = ghb + BDIM * H3;             // B*H
    float* gen  = th2 + BDIM * HDIM;           // B*V
    float* css  = gen + (size_t)BDIM * VDIM;   // B*S
    float* atC  = css + BDIM * SDIM;           // B*32*H
    float* atM  = atC + (size_t)BDIM * NSUB * HDIM;   // 256
    float* atZ  = atM + BDIM * NSUB;
    float* gM   = atZ + BDIM * NSUB;
    float* gZ   = gM  + BDIM * NSUB;
    float* argV = gZ  + BDIM * NSUB;           // 256
    int*   argI = (int*)(argV + BDIM * NSUB);  // 256

    boot_kernel<<<512, 256, 0, stream>>>(dout, cls, hA, x, emb, thb, ghb,
                                         attn_b, b_hh);
    combo_kernel<<<256, 512, 0, stream>>>(enc, thb, th2, css, atC, atM, atZ,
                                          gen, gM, gZ, 0);
    mix_kernel<<<16, 1024, 0, stream>>>(enc, css, inputs, argV, argI, emb,
                                        dout, x, atC, atM, atZ, 0, 0);

    for (int t = 0; t < TLEN - 1; t++) {
        const float* hin  = (t & 1) ? hB : hA;
        float*       hout = (t & 1) ? hA : hB;
        grufull_kernel<<<HDIM, 256, 0, stream>>>(w_ih, b_ih, x, ghb, hin, hout);
        bigmv_kernel<<<(NROWS + 15) / 16, 256, 0, stream>>>(
            copy_w, copy_b, out_w, out_b, attn_w, attn_b, w_hh, b_hh,
            hout, th2, gen, thb, ghb);
        combo_kernel<<<256, 512, 0, stream>>>(enc, thb, th2, css, atC, atM, atZ,
                                              gen, gM, gZ, 1);
        tailc_kernel<<<256, 1024, 0, stream>>>(gen, css, inputs, gM, gZ,
                                               dout, argV, argI, t);
        mix_kernel<<<16, 1024, 0, stream>>>(enc, css, inputs, argV, argI, emb,
                                            dout, x, atC, atM, atZ, t, 1);
    }
}

// Round 13
// 2987.102 us; speedup vs baseline: 1.4698x; 1.4698x over previous
//
#include <hip/hip_runtime.h>
#include <hip/hip_bf16.h>
#include <math.h>

#define HDIM 768
#define SDIM 512
#define VDIM 30522
#define BDIM 8
#define TLEN 32
#define H3   2304
#define VT   31034          // V + S
#define NEGV -1.0e6f
#define OFF2 ((size_t)BDIM * TLEN * VT)   // 7944704
#define NSUB 32                            // s/v subslices
#define SSL  16                            // SDIM / NSUB
#define VSL  954                           // ceil(VDIM/32)
#define NROWS (HDIM + VDIM + HDIM + H3)    // 34362 bigmv rows

// ---------------------------------------------------------------------------
// Boot: dout init; h0 = 0; th0 = attn_b; gh0 = b_hh; x sel/emb init.
// ---------------------------------------------------------------------------
__global__ __launch_bounds__(256) void boot_kernel(
    float* __restrict__ dout, const int* __restrict__ cls,
    float* __restrict__ hA, float* __restrict__ x,
    const float* __restrict__ emb, float* __restrict__ thb,
    float* __restrict__ ghb, const float* __restrict__ attn_b,
    const float* __restrict__ b_hh)
{
    int gidx = blockIdx.x * 256 + threadIdx.x;
    int stride = gridDim.x * 256;
    float clsv = (float)cls[0];
    for (int i = gidx; i < BDIM * VT; i += stride) {
        int b = i / VT, v = i % VT;
        dout[(size_t)b * TLEN * VT + v] = (v == 0) ? clsv : 0.f;
    }
    if (gidx < BDIM) dout[OFF2 + (size_t)gidx * TLEN] = 1.0f;
    for (int i = gidx; i < BDIM * HDIM; i += stride) {
        int b = i / HDIM, j = i % HDIM;
        hA[i] = 0.f;
        x[b * H3 + HDIM + j] = 0.f;
        x[b * H3 + 2 * HDIM + j] = emb[HDIM + j];
        thb[i] = attn_b[j];
    }
    for (int i = gidx; i < BDIM * H3; i += stride)
        ghb[i] = b_hh[i % H3];
}

// ---------------------------------------------------------------------------
// grufull: block j (768 blocks x 256 thr). 4 waves split K=2304 into 576-
// element chunks; per-wave partials for all 3 gates x 8 batches combined in
// LDS in fixed wave order; thread b<8 does the GRU nonlinearity.
// ---------------------------------------------------------------------------
__global__ __launch_bounds__(256) void grufull_kernel(
    const float* __restrict__ w_ih, const float* __restrict__ b_ih,
    const float* __restrict__ x, const float* __restrict__ ghb,
    const float* __restrict__ hin, float* __restrict__ hout)
{
    __shared__ float gp[4][3][BDIM];
    int tid = threadIdx.x, w = tid >> 6, lane = tid & 63;
    int j = blockIdx.x;

    const float4* wr = (const float4*)(w_ih + (size_t)j * H3);
    const float4* wz = (const float4*)(w_ih + (size_t)(HDIM + j) * H3);
    const float4* wn = (const float4*)(w_ih + (size_t)(2 * HDIM + j) * H3);

    float ar[8], az[8], an[8];
#pragma unroll
    for (int b = 0; b < 8; b++) { ar[b] = 0.f; az[b] = 0.f; an[b] = 0.f; }

    int k0 = w * 144;                       // 144 float4 = 576 floats per wave
    for (int k4 = k0 + lane; k4 < k0 + 144; k4 += 64) {
        float4 w4r = wr[k4], w4z = wz[k4], w4n = wn[k4];
#pragma unroll
        for (int b = 0; b < 8; b++) {
            float4 x4 = ((const float4*)(x + b * H3))[k4];
            ar[b] += w4r.x * x4.x + w4r.y * x4.y + w4r.z * x4.z + w4r.w * x4.w;
            az[b] += w4z.x * x4.x + w4z.y * x4.y + w4z.z * x4.z + w4z.w * x4.w;
            an[b] += w4n.x * x4.x + w4n.y * x4.y + w4n.z * x4.z + w4n.w * x4.w;
        }
    }
#pragma unroll
    for (int b = 0; b < 8; b++) {
        float vr = ar[b], vz = az[b], vn = an[b];
        for (int off = 32; off; off >>= 1) {
            vr += __shfl_down(vr, off, 64);
            vz += __shfl_down(vz, off, 64);
            vn += __shfl_down(vn, off, 64);
        }
        ar[b] = vr; az[b] = vz; an[b] = vn;
    }
    if (lane == 0) {
#pragma unroll
        for (int b = 0; b < 8; b++) {
            gp[w][0][b] = ar[b];
            gp[w][1][b] = az[b];
            gp[w][2][b] = an[b];
        }
    }
    __syncthreads();
    if (tid < BDIM) {
        int b = tid;
        float gir = gp[0][0][b] + gp[1][0][b] + gp[2][0][b] + gp[3][0][b] + b_ih[j];
        float giz = gp[0][1][b] + gp[1][1][b] + gp[2][1][b] + gp[3][1][b] + b_ih[HDIM + j];
        float gin = gp[0][2][b] + gp[1][2][b] + gp[2][2][b] + gp[3][2][b] + b_ih[2 * HDIM + j];
        float ghr = ghb[b * H3 + j];
        float ghz = ghb[b * H3 + HDIM + j];
        float ghn = ghb[b * H3 + 2 * HDIM + j];
        float r = 1.f / (1.f + expf(-(gir + ghr)));
        float z = 1.f / (1.f + expf(-(giz + ghz)));
        float n = tanhf(gin + r * ghn);
        hout[b * HDIM + j] = (1.f - z) * n + z * hin[b * HDIM + j];
    }
}

// ---------------------------------------------------------------------------
// Per-row routing for bigmv.
// ---------------------------------------------------------------------------
struct RowT { const float* w; const float* bias; float* dst; int stride; int neg; };

__device__ __forceinline__ RowT row_info(
    int r,
    const float* copy_w, const float* copy_b,
    const float* out_w,  const float* out_b,
    const float* attn_w, const float* attn_b,
    const float* w_hh,   const float* b_hh,
    float* th2, float* gen, float* thb, float* ghb)
{
    RowT t;
    if (r < HDIM) {
        t.w = copy_w + (size_t)r * HDIM; t.bias = copy_b + r;
        t.dst = th2 + r; t.stride = HDIM; t.neg = 0;
    } else if (r < HDIM + VDIM) {
        int v = r - HDIM;
        t.w = out_w + (size_t)v * HDIM; t.bias = out_b + v;
        t.dst = gen + v; t.stride = VDIM; t.neg = (v == 0);
    } else if (r < 2 * HDIM + VDIM) {
        int rr = r - HDIM - VDIM;
        t.w = attn_w + (size_t)rr * HDIM; t.bias = attn_b + rr;
        t.dst = thb + rr; t.stride = HDIM; t.neg = 0;
    } else {
        int rr = r - 2 * HDIM - VDIM;
        t.w = w_hh + (size_t)rr * HDIM; t.bias = b_hh + rr;
        t.dst = ghb + rr; t.stride = H3; t.neg = 0;
    }
    return t;
}

// ---------------------------------------------------------------------------
// bigmv: stream copy_w | out_w | attn_w | w_hh against x read directly from
// global (hp = 24 KB, L1/L2-hot). 2148 blocks x 256 thr; 4 waves x 4 rows.
// NOTE: no min-waves occupancy hint — (256,8) capped VGPRs at 32 and caused
// scratch spills (R10: FETCH 52->97 MB, WRITE 1.5->129 MB, dur 2x).
// ---------------------------------------------------------------------------
__global__ __launch_bounds__(256) void bigmv_kernel(
    const float* __restrict__ copy_w, const float* __restrict__ copy_b,
    const float* __restrict__ out_w,  const float* __restrict__ out_b,
    const float* __restrict__ attn_w, const float* __restrict__ attn_b,
    const float* __restrict__ w_hh,   const float* __restrict__ b_hh,
    const float* __restrict__ hp, float* __restrict__ th2,
    float* __restrict__ gen, float* __restrict__ thb,
    float* __restrict__ ghb)
{
    int wid = threadIdx.x >> 6, lane = threadIdx.x & 63;
    int r0 = blockIdx.x * 16 + wid * 4;
    if (r0 >= NROWS) return;

    int rc1 = min(r0 + 1, NROWS - 1);
    int rc2 = min(r0 + 2, NROWS - 1), rc3 = min(r0 + 3, NROWS - 1);
    RowT t0 = row_info(r0,  copy_w, copy_b, out_w, out_b, attn_w, attn_b,
                       w_hh, b_hh, th2, gen, thb, ghb);
    RowT t1 = row_info(rc1, copy_w, copy_b, out_w, out_b, attn_w, attn_b,
                       w_hh, b_hh, th2, gen, thb, ghb);
    RowT t2 = row_info(rc2, copy_w, copy_b, out_w, out_b, attn_w, attn_b,
                       w_hh, b_hh, th2, gen, thb, ghb);
    RowT t3 = row_info(rc3, copy_w, copy_b, out_w, out_b, attn_w, attn_b,
                       w_hh, b_hh, th2, gen, thb, ghb);

    float a0[8], a1[8], a2[8], a3[8];
#pragma unroll
    for (int b = 0; b < 8; b++) { a0[b] = 0.f; a1[b] = 0.f; a2[b] = 0.f; a3[b] = 0.f; }

    const float4* w0 = (const float4*)t0.w;
    const float4* w1 = (const float4*)t1.w;
    const float4* w2 = (const float4*)t2.w;
    const float4* w3 = (const float4*)t3.w;
    const float4* xb = (const float4*)hp;

#pragma unroll
    for (int i = 0; i < 3; i++) {
        int k4 = lane + i * 64;
        float4 q0 = w0[k4], q1 = w1[k4], q2 = w2[k4], q3 = w3[k4];
#pragma unroll
        for (int b = 0; b < 8; b++) {
            float4 x4 = xb[b * 192 + k4];
            a0[b] += q0.x * x4.x + q0.y * x4.y + q0.z * x4.z + q0.w * x4.w;
            a1[b] += q1.x * x4.x + q1.y * x4.y + q1.z * x4.z + q1.w * x4.w;
            a2[b] += q2.x * x4.x + q2.y * x4.y + q2.z * x4.z + q2.w * x4.w;
            a3[b] += q3.x * x4.x + q3.y * x4.y + q3.z * x4.z + q3.w * x4.w;
        }
    }
#pragma unroll
    for (int b = 0; b < 8; b++) {
        float v0 = a0[b], v1 = a1[b], v2 = a2[b], v3 = a3[b];
        for (int off = 32; off; off >>= 1) {
            v0 += __shfl_down(v0, off, 64);
            v1 += __shfl_down(v1, off, 64);
            v2 += __shfl_down(v2, off, 64);
            v3 += __shfl_down(v3, off, 64);
        }
        a0[b] = v0; a1[b] = v1; a2[b] = v2; a3[b] = v3;
    }
    if (lane == 0) {
        float bb0 = t0.bias[0], bb1 = t1.bias[0], bb2 = t2.bias[0], bb3 = t3.bias[0];
#pragma unroll
        for (int b = 0; b < 8; b++) {
            t0.dst[(size_t)b * t0.stride] = t0.neg ? NEGV : a0[b] + bb0;
            if (r0 + 1 < NROWS) t1.dst[(size_t)b * t1.stride] = t1.neg ? NEGV : a1[b] + bb1;
            if (r0 + 2 < NROWS) t2.dst[(size_t)b * t2.stride] = t2.neg ? NEGV : a2[b] + bb2;
            if (r0 + 3 < NROWS) t3.dst[(size_t)b * t3.stride] = t3.neg ? NEGV : a3[b] + bb3;
        }
    }
}

// ---------------------------------------------------------------------------
// combo: block (b,sub): one enc pass. Each wave dots 2 enc rows against th
// (scores t+1) AND th2 (css), KEEPING the enc fragments in registers; after
// the softmax partial, per-wave context partials go to LDS and are summed in
// fixed wave order. Then gen-stats slice. 256 blocks x 512.
// ---------------------------------------------------------------------------
__global__ __launch_bounds__(512) void combo_kernel(
    const float* __restrict__ enc, const float* __restrict__ thb,
    const float* __restrict__ th2, float* __restrict__ css,
    float* __restrict__ atC, float* __restrict__ atM, float* __restrict__ atZ,
    const float* __restrict__ gen, float* __restrict__ gM,
    float* __restrict__ gZ, int do_cg)
{
    __shared__ float sth[HDIM];
    __shared__ float sth2[HDIM];
    __shared__ float swe[SSL];
    __shared__ float red[8];
    __shared__ float4 part[8][HDIM / 4];   // 24 KB
    int blk = blockIdx.x, b = blk >> 5, sub = blk & 31;
    int tid = threadIdx.x, wid = tid >> 6, lane = tid & 63;
    int slo = sub * SSL;

    for (int i = tid; i < HDIM; i += 512) {
        sth[i]  = thb[b * HDIM + i];
        sth2[i] = th2[b * HDIM + i];
    }
    __syncthreads();

    // dual dots: 2 s per wave; keep enc fragments live
    float4 e0[3], e1[3];
#pragma unroll
    for (int j = 0; j < 2; j++) {
        int sl = wid * 2 + j, s = slo + sl;
        const float4* er = (const float4*)(enc + ((size_t)b * SDIM + s) * HDIM);
        float a1 = 0.f, a2 = 0.f;
#pragma unroll
        for (int i = 0; i < 3; i++) {
            float4 e = er[lane + i * 64];
            if (j == 0) e0[i] = e; else e1[i] = e;
            float4 t1 = ((const float4*)sth)[lane + i * 64];
            float4 t2 = ((const float4*)sth2)[lane + i * 64];
            a1 += e.x * t1.x + e.y * t1.y + e.z * t1.z + e.w * t1.w;
            a2 += e.x * t2.x + e.y * t2.y + e.z * t2.z + e.w * t2.w;
        }
        for (int off = 32; off; off >>= 1) {
            a1 += __shfl_down(a1, off, 64);
            a2 += __shfl_down(a2, off, 64);
        }
        if (lane == 0) {
            swe[sl] = a1;
            if (do_cg) css[b * SDIM + s] = a2;
        }
    }
    __syncthreads();

    // softmax partial over the 16 scores
    if (tid == 0) {
        float m = swe[0];
        for (int i = 1; i < SSL; i++) m = fmaxf(m, swe[i]);
        float z = 0.f;
        for (int i = 0; i < SSL; i++) { float e = expf(swe[i] - m); swe[i] = e; z += e; }
        atM[b * NSUB + sub] = m;
        atZ[b * NSUB + sub] = z;
    }
    __syncthreads();

    // per-wave context partial from live registers -> LDS
    {
        float wq0 = swe[wid * 2], wq1 = swe[wid * 2 + 1];
#pragma unroll
        for (int i = 0; i < 3; i++) {
            float4 p;
            p.x = wq0 * e0[i].x + wq1 * e1[i].x;
            p.y = wq0 * e0[i].y + wq1 * e1[i].y;
            p.z = wq0 * e0[i].z + wq1 * e1[i].z;
            p.w = wq0 * e0[i].w + wq1 * e1[i].w;
            part[wid][lane + i * 64] = p;
        }
    }
    __syncthreads();
    if (tid < HDIM / 4) {
        float4 acc = part[0][tid];
#pragma unroll
        for (int w = 1; w < 8; w++) {
            float4 p = part[w][tid];
            acc.x += p.x; acc.y += p.y; acc.z += p.z; acc.w += p.w;
        }
        ((float4*)(atC + ((size_t)b * NSUB + sub) * HDIM))[tid] = acc;
    }

    if (!do_cg) return;

    // gen stats over v-slice
    int vlo = sub * VSL, vhi = min(VDIM, vlo + VSL);
    const float* grow = gen + (size_t)b * VDIM;
    float m = -INFINITY;
    for (int v = vlo + tid; v < vhi; v += 512) m = fmaxf(m, grow[v]);
    for (int off = 32; off; off >>= 1) m = fmaxf(m, __shfl_xor(m, off, 64));
    if (lane == 0) red[wid] = m;
    __syncthreads();
    float M = red[0];
#pragma unroll
    for (int w = 1; w < 8; w++) M = fmaxf(M, red[w]);
    float z = 0.f;
    for (int v = vlo + tid; v < vhi; v += 512) z += expf(grow[v] - M);
    for (int off = 32; off; off >>= 1) z += __shfl_xor(z, off, 64);
    __syncthreads();
    if (lane == 0) red[wid] = z;
    __syncthreads();
    if (tid == 0) {
        float Z = 0.f;
#pragma unroll
        for (int w = 0; w < 8; w++) Z += red[w];
        gM[b * NSUB + sub] = M;
        gZ[b * NSUB + sub] = Z;
    }
}

// ---------------------------------------------------------------------------
// tailc: copy agg + M/Z combine (32 partials, fixed order) + log-prob slice
// + argmax partials. 256 blocks x 1024 (32 v-slices per batch).
// ---------------------------------------------------------------------------
__global__ __launch_bounds__(1024) void tailc_kernel(
    const float* __restrict__ gen, const float* __restrict__ css,
    const int* __restrict__ inputs, const float* __restrict__ genM,
    const float* __restrict__ genZ, float* __restrict__ dout,
    float* __restrict__ argV, int* __restrict__ argI, int t)
{
    __shared__ int   toks[SDIM];
    __shared__ float csss[SDIM];
    __shared__ float aggv[SDIM];
    __shared__ unsigned char ffl[SDIM];
    __shared__ float redf[1024];
    __shared__ int   redi[1024];
    int blk = blockIdx.x, b = blk >> 5, sub = blk & 31;
    int tid = threadIdx.x;

    if (tid < SDIM) {
        toks[tid] = inputs[b * SDIM + tid];
        csss[tid] = css[b * SDIM + tid];
    }
    __syncthreads();

    if (tid < SDIM) {
        int tok = toks[tid]; int isf = 0; float agg = -INFINITY;
        if (tok != 0) {
            isf = 1;
            for (int s2 = 0; s2 < tid; s2++)
                if (toks[s2] == tok) { isf = 0; break; }
            if (isf) {
                float ss = 0.f;
                for (int s2 = tid; s2 < SDIM; s2++)
                    if (toks[s2] == tok) ss += csss[s2];
                agg = ss;
            }
        }
        ffl[tid] = (unsigned char)isf;
        aggv[tid] = agg;
    }
    __syncthreads();

    redf[tid] = (tid < SDIM && ffl[tid]) ? aggv[tid] : -INFINITY;
    __syncthreads();
    for (int off = 512; off; off >>= 1) {
        if (tid < off) redf[tid] = fmaxf(redf[tid], redf[tid + off]);
        __syncthreads();
    }
    float m9 = redf[0]; __syncthreads();
    redf[tid] = (tid < SDIM && ffl[tid] && m9 > -INFINITY)
                    ? expf(aggv[tid] - m9) : 0.f;
    __syncthreads();
    for (int off = 512; off; off >>= 1) {
        if (tid < off) redf[tid] += redf[tid + off];
        __syncthreads();
    }
    float z9 = redf[0]; __syncthreads();

    float M = genM[b * NSUB + 0];
#pragma unroll
    for (int i = 1; i < NSUB; i++) M = fmaxf(M, genM[b * NSUB + i]);
    if (m9 > -INFINITY) M = fmaxf(M, m9);
    float Z = 0.f;
#pragma unroll
    for (int i = 0; i < NSUB; i++)
        Z += genZ[b * NSUB + i] * expf(genM[b * NSUB + i] - M);
    if (m9 > -INFINITY) Z += z9 * expf(m9 - M);
    float invZ = 1.f / Z;

    const float* grow = gen + (size_t)b * VDIM;
    float* orow = dout + ((size_t)b * TLEN + t + 1) * VT;
    int vlo = sub * VSL, vhi = min(VDIM, vlo + VSL);
    float best = -INFINITY; int bidx = 2147483647;
    for (int v = vlo + tid; v < vhi; v += 1024) {
        float pg = expf(grow[v] - M) * invZ;
        float lp = logf(pg + 1e-10f);
        orow[v] = lp;
        if (lp > best) { best = lp; bidx = v; }
    }
    if (sub == 0 && tid < SDIM) orow[VDIM + tid] = logf(1e-10f);
    __syncthreads();

    if (tid < SDIM && ffl[tid]) {
        int tok = toks[tid];
        if (tok >= vlo && tok < vhi) {
            float pc = expf(aggv[tid] - M) * invZ;
            float pg = expf(grow[tok] - M) * invZ;
            float lp = logf(pg + pc + 1e-10f);
            orow[tok] = lp;
            if (lp > best || (lp == best && tok < bidx)) { best = lp; bidx = tok; }
        }
    }
    redf[tid] = best; redi[tid] = bidx; __syncthreads();
    for (int off = 512; off; off >>= 1) {
        if (tid < off) {
            float v2 = redf[tid + off]; int i2 = redi[tid + off];
            if (v2 > redf[tid] || (v2 == redf[tid] && i2 < redi[tid])) {
                redf[tid] = v2; redi[tid] = i2;
            }
        }
        __syncthreads();
    }
    if (tid == 0) { argV[b * NSUB + sub] = redf[0]; argI[b * NSUB + sub] = redi[0]; }
}

// ---------------------------------------------------------------------------
// mix: blocks 0..7 = tail_d (argmax over 32 partials asc, samp, selread+embed)
//      blocks 8..15 = attn_fin (32-partial flash combine -> x[:,0:H)).
// ---------------------------------------------------------------------------
__global__ __launch_bounds__(1024) void mix_kernel(
    const float* __restrict__ enc, const float* __restrict__ css,
    const int* __restrict__ inputs, const float* __restrict__ argV,
    const int* __restrict__ argI, const float* __restrict__ emb,
    float* __restrict__ dout, float* __restrict__ x,
    const float* __restrict__ atC, const float* __restrict__ atM,
    const float* __restrict__ atZ, int t, int do_tail)
{
    __shared__ int   toks[SDIM];
    __shared__ float csss[SDIM];
    __shared__ float redf[1024];
    __shared__ int   mlist[SDIM];
    __shared__ float mscore[SDIM];
    __shared__ int   wcnt[16], woff[16];
    __shared__ int   mtot;
    int bid = blockIdx.x, tid = threadIdx.x;

    if (bid >= BDIM) {
        int b = bid - BDIM;
        if (tid < HDIM) {
            float M = atM[b * NSUB];
#pragma unroll
            for (int i = 1; i < NSUB; i++) M = fmaxf(M, atM[b * NSUB + i]);
            float Z = 0.f, acc = 0.f;
#pragma unroll
            for (int i = 0; i < NSUB; i++) {
                float sc = expf(atM[b * NSUB + i] - M);
                Z += atZ[b * NSUB + i] * sc;
                acc += atC[((size_t)b * NSUB + i) * HDIM + tid] * sc;
            }
            x[b * H3 + tid] = acc / Z;
        }
        return;
    }
    if (!do_tail) return;

    int b = bid;
    float best = argV[b * NSUB + 0]; int samp = argI[b * NSUB + 0];
#pragma unroll
    for (int i = 1; i < NSUB; i++) {
        float v = argV[b * NSUB + i];
        if (v > best) { best = v; samp = argI[b * NSUB + i]; }
    }
    if (tid == 0) dout[OFF2 + (size_t)b * TLEN + t + 1] = (float)samp;

    if (tid < SDIM) {
        toks[tid] = inputs[b * SDIM + tid];
        csss[tid] = css[b * SDIM + tid];
    }
    __syncthreads();

    int flag = (tid < SDIM) ? (toks[tid] == samp) : 0;
    redf[tid] = flag ? fabsf(csss[tid]) : 0.f;
    __syncthreads();
    for (int off = 512; off; off >>= 1) {
        if (tid < off) redf[tid] += redf[tid + off];
        __syncthreads();
    }
    float den = fmaxf(redf[0], 1e-12f);
    __syncthreads();

    unsigned long long mk = __ballot(flag);
    int wv = tid >> 6, ln = tid & 63;
    if (ln == 0) wcnt[wv] = __popcll(mk);
    __syncthreads();
    if (tid == 0) {
        int o = 0;
        for (int w = 0; w < 16; w++) { woff[w] = o; o += wcnt[w]; }
        mtot = o;
    }
    __syncthreads();
    if (flag) {
        int pos = woff[wv] + __popcll(mk & ((1ULL << ln) - 1ULL));
        mlist[pos] = tid;
        mscore[pos] = csss[tid] / den;
    }
    __syncthreads();
    int mc = mtot;

    if (tid < HDIM) {
        float sel = 0.f;
        for (int mI = 0; mI < mc; mI++)
            sel += mscore[mI] * enc[((size_t)b * SDIM + mlist[mI]) * HDIM + tid];
        x[b * H3 + HDIM + tid] = sel;
        int ic = (samp > VDIM) ? 3 : samp;
        if (ic >= VDIM) ic = VDIM - 1;
        x[b * H3 + 2 * HDIM + tid] = emb[(size_t)ic * HDIM + tid];
    }
}

// ---------------------------------------------------------------------------
extern "C" void kernel_launch(void* const* d_in, const int* in_sizes, int n_in,
                              void* d_out, int out_size, void* d_ws, size_t ws_size,
                              hipStream_t stream)
{
    const float* enc    = (const float*)d_in[0];
    const int*   inputs = (const int*)d_in[1];
    const int*   cls    = (const int*)d_in[2];
    const float* emb    = (const float*)d_in[4];
    const float* attn_w = (const float*)d_in[5];
    const float* attn_b = (const float*)d_in[6];
    const float* copy_w = (const float*)d_in[7];
    const float* copy_b = (const float*)d_in[8];
    const float* w_ih   = (const float*)d_in[9];
    const float* w_hh   = (const float*)d_in[10];
    const float* b_ih   = (const float*)d_in[11];
    const float* b_hh   = (const float*)d_in[12];
    const float* out_w  = (const float*)d_in[13];
    const float* out_b  = (const float*)d_in[14];
    float* dout = (float*)d_out;

    float* ws   = (float*)d_ws;
    float* hA   = ws;                          // B*H
    float* hB   = hA  + BDIM * HDIM;           // B*H
    float* x    = hB  + BDIM * HDIM;           // B*H3
    float* thb  = x   + BDIM * H3;             // B*H
    float* ghb  = thb + BDIM * HDIM;           // B*H3
    float* th2  = ghb + BDIM * H3;             // B*H
    float* gen  = th2 + BDIM * HDIM;           // B*V
    float* css  = gen + (size_t)BDIM * VDIM;   // B*S
    float* atC  = css + BDIM * SDIM;           // B*32*H
    float* atM  = atC + (size_t)BDIM * NSUB * HDIM;   // 256
    float* atZ  = atM + BDIM * NSUB;
    float* gM   = atZ + BDIM * NSUB;
    float* gZ   = gM  + BDIM * NSUB;
    float* argV = gZ  + BDIM * NSUB;           // 256
    int*   argI = (int*)(argV + BDIM * NSUB);  // 256

    boot_kernel<<<512, 256, 0, stream>>>(dout, cls, hA, x, emb, thb, ghb,
                                         attn_b, b_hh);
    combo_kernel<<<256, 512, 0, stream>>>(enc, thb, th2, css, atC, atM, atZ,
                                          gen, gM, gZ, 0);
    mix_kernel<<<16, 1024, 0, stream>>>(enc, css, inputs, argV, argI, emb,
                                        dout, x, atC, atM, atZ, 0, 0);

    for (int t = 0; t < TLEN - 1; t++) {
        const float* hin  = (t & 1) ? hB : hA;
        float*       hout = (t & 1) ? hA : hB;
        grufull_kernel<<<HDIM, 256, 0, stream>>>(w_ih, b_ih, x, ghb, hin, hout);
        bigmv_kernel<<<(NROWS + 15) / 16, 256, 0, stream>>>(
            copy_w, copy_b, out_w, out_b, attn_w, attn_b, w_hh, b_hh,
            hout, th2, gen, thb, ghb);
        combo_kernel<<<256, 512, 0, stream>>>(enc, thb, th2, css, atC, atM, atZ,
                                              gen, gM, gZ, 1);
        tailc_kernel<<<256, 1024, 0, stream>>>(gen, css, inputs, gM, gZ,
                                               dout, argV, argI, t);
        mix_kernel<<<16, 1024, 0, stream>>>(enc, css, inputs, argV, argI, emb,
                                            dout, x, atC, atM, atZ, t, 1);
    }
}